// Round 8
// baseline (5048.753 us; speedup 1.0000x reference)
//
#include <hip/hip_runtime.h>
#include <math.h>

// PhasedLSTM: B=64, T=512, H=768. fp32 in/out.
// Persistent kernel. R8 (3rd resubmit; R6/R7 benches = GPUAcquisitionTimeout,
// kernel never executed): TAGGED h-exchange for gx modes: h stored as 8B
//   units {2xbf16, u32 step tag} (sc0 sc1). Consumers poll the DATA lines for
//   tag==t -- on success the h values are already in registers. Removes
//   per-step producer vmcnt(0) drain AND flag store->poll hop (3 RTs -> 1).
//   Safety (re-audited): h-store is after the barrier following ALL 4
//   waves' polls; 4 waves x 24 producers = all 96 blocks covered; so J
//   reaching step t+1's store implies every consumer finished reading J's
//   step-t data. Skew>1 impossible; no deadlock (induction from memset).
//   Sticky bounded-spin watchdog (2^20 rounds) converts any protocol hang
//   into a visible wrong-answer failure instead of a wedged GPU.
//   Modes: 0=xf, 1=xb (legacy flag protocol), 2=gx f32, 3=gx f16 (tagged).

#define HDIM 768
#define BDIM 64
#define TDIM 512
#define G_BLOCKS 96
#define ND 8   // hidden dims per block (768/96)

typedef float f32x4 __attribute__((ext_vector_type(4)));
typedef float f32x2 __attribute__((ext_vector_type(2)));
typedef __bf16 bf16x8 __attribute__((ext_vector_type(8)));
typedef _Float16 f16x2 __attribute__((ext_vector_type(2)));
typedef int i32x4 __attribute__((ext_vector_type(4)));
typedef int i32x2 __attribute__((ext_vector_type(2)));

// workspace layout (bytes)
#define OFF_FLAGS 0                                     // 384 x 64B lines (modes 0/1)
#define OFF_HBUF0 24576                                 // tagged: 64*384*8 = 196608
#define OFF_HBUF1 (24576 + 196608)
#define OFF_KTAB  (24576 + 2*196608)                    // 417792; 512*768*4
#define OFF_WT    (OFF_KTAB + (size_t)512*768*4)        // + 1.5MB
#define OFF_XB    (OFF_WT + (size_t)3072*1536*2)        // + 9.4MB
#define WS_NEED_FULL (OFF_XB + (size_t)512*64*768*2)    // ~61.8MB (mode 1)
#define OFF_GX    OFF_XB                                // gx replaces xb
#define WS_NEED_GXF32 (OFF_GX + (size_t)32768*3072*4)   // ~414MB
#define WS_NEED_GXF16 (OFF_GX + (size_t)32768*3072*2)   // ~213MB

// ---------------- prep kernels ----------------

__global__ void k_wcomb(const float* __restrict__ W, const float* __restrict__ U,
                        __bf16* __restrict__ WT) {
  __shared__ __bf16 tile[32][33];
  int tk = blockIdx.x % 48;   // k tile (1536/32)
  int tn = blockIdx.x / 48;   // n tile (3072/32)
  int tx = threadIdx.x & 31, ty = threadIdx.x >> 5; // 32 x 8
  int k0 = tk * 32, n0 = tn * 32;
#pragma unroll
  for (int i = 0; i < 4; ++i) {
    int k = k0 + ty + 8 * i;
    int n = n0 + tx;
    const float* M = (k < 768) ? W : U;
    int r = (k < 768) ? k : k - 768;
    float v;
    if (n < 2304)
      v = M[(size_t)r * 3072 + n] + M[(size_t)(768 + r) * 3072 + n] +
          M[(size_t)(1536 + r) * 3072 + n];
    else
      v = M[(size_t)(2304 + r) * 3072 + n];
    tile[ty + 8 * i][tx] = (__bf16)v;
  }
  __syncthreads();
#pragma unroll
  for (int i = 0; i < 4; ++i) {
    int n = n0 + ty + 8 * i;
    int k = k0 + tx;
    WT[(size_t)n * 1536 + k] = tile[tx][ty + 8 * i];
  }
}

__global__ void k_ktab(const float* __restrict__ tau, const float* __restrict__ shift,
                       float* __restrict__ kT) {
  int idx = blockIdx.x * 256 + threadIdx.x;  // t*768 + d
  int d = idx % 768, t = idx / 768;
  float bb = tau[d];
  float a = (float)t - shift[d];
  const float PI = 3.14159265358979323846f;
  float fm = bb / PI * atanf(tanf(PI * (a / bb - 0.5f))) + bb * 0.5f;
  float phi = fm / (bb + 1e-8f);
  float kv;
  if (phi < 0.5f * 0.05f)      kv = 2.0f * phi / 0.05f;
  else if (phi < 0.05f)        kv = 2.0f - 2.0f * phi / 0.05f;
  else                         kv = 0.001f * phi;
  kT[idx] = kv;
}

__global__ void k_xb(const float* __restrict__ x, __bf16* __restrict__ xb) {
  int idx = blockIdx.x * 256 + threadIdx.x;  // (t*64+b)*768 + k
  int k = idx % 768;
  int tb = idx / 768;
  int b = tb % 64, t = tb / 64;
  xb[idx] = (__bf16)x[((size_t)b * 512 + t) * 768 + k];
}

// gx[m][n] = sum_{k<768} x_bf16[m][k] * WT[n][k], m=t*64+b, n in [0,3072)
template <int F16OUT>
__global__ __launch_bounds__(256, 2)
void k_xgemm(const float* __restrict__ x, const __bf16* __restrict__ Wt,
             void* __restrict__ Cv) {
  __shared__ __align__(16) unsigned char AsB[128 * 128];
  __shared__ __align__(16) unsigned char BsB[128 * 128];
  const int tid = threadIdx.x;
  const int wave = tid >> 6, lane = tid & 63;
  const int quad = lane >> 4, l15 = lane & 15;
  const int wr = wave >> 1, wc = wave & 1;
  const int mt = blockIdx.x / 24, nt = blockIdx.x % 24;
  const int m0 = mt * 128, n0 = nt * 128;

  f32x4 acc[4][4];
#pragma unroll
  for (int i = 0; i < 4; ++i)
#pragma unroll
    for (int jj = 0; jj < 4; ++jj) acc[i][jj] = (f32x4){0.f, 0.f, 0.f, 0.f};

  for (int kt = 0; kt < 12; ++kt) {
#pragma unroll
    for (int s0 = 0; s0 < 4; ++s0) {
      int s = s0 * 256 + tid;
      int row = s >> 3, part = s & 7;
      int sw = (row & 7) << 4;
      int m = m0 + row;
      const float* ap = x + ((size_t)(m & 63) * 512 + (m >> 6)) * 768 + kt * 64 + part * 8;
      f32x4 a0 = *(const f32x4*)ap;
      f32x4 a1 = *(const f32x4*)(ap + 4);
      bf16x8 av;
#pragma unroll
      for (int q = 0; q < 4; ++q) { av[q] = (__bf16)a0[q]; av[q + 4] = (__bf16)a1[q]; }
      *(bf16x8*)&AsB[row * 128 + ((part * 16) ^ sw)] = av;
      i32x4 vb = *(const i32x4*)((const unsigned char*)Wt +
                                 (size_t)(n0 + row) * 3072 + kt * 128 + part * 16);
      *(i32x4*)&BsB[row * 128 + ((part * 16) ^ sw)] = vb;
    }
    __syncthreads();
#pragma unroll
    for (int ks = 0; ks < 2; ++ks) {
      const int cb = (ks * 32 + quad * 8) * 2;
      bf16x8 af[4], bfr[4];
#pragma unroll
      for (int f = 0; f < 4; ++f) {
        int ar = wr * 64 + f * 16 + l15;
        af[f] = *(const bf16x8*)&AsB[ar * 128 + (cb ^ ((ar & 7) << 4))];
        int br = wc * 64 + f * 16 + l15;
        bfr[f] = *(const bf16x8*)&BsB[br * 128 + (cb ^ ((br & 7) << 4))];
      }
#pragma unroll
      for (int fm = 0; fm < 4; ++fm)
#pragma unroll
        for (int fn = 0; fn < 4; ++fn)
          acc[fm][fn] = __builtin_amdgcn_mfma_f32_16x16x32_bf16(af[fm], bfr[fn],
                                                                acc[fm][fn], 0, 0, 0);
    }
    __syncthreads();
  }
#pragma unroll
  for (int fm = 0; fm < 4; ++fm) {
    int m = m0 + wr * 64 + fm * 16 + quad * 4;
#pragma unroll
    for (int fn = 0; fn < 4; ++fn) {
      int n = n0 + wc * 64 + fn * 16 + l15;
#pragma unroll
      for (int r = 0; r < 4; ++r) {
        if constexpr (F16OUT)
          ((_Float16*)Cv)[(size_t)(m + r) * 3072 + n] = (_Float16)acc[fm][fn][r];
        else
          ((float*)Cv)[(size_t)(m + r) * 3072 + n] = acc[fm][fn][r];
      }
    }
  }
}

// ---------------- asm memory helpers ----------------
__device__ __forceinline__ i32x4 ldg_c16(const void* p) {
  i32x4 r;
  asm volatile("global_load_dwordx4 %0, %1, off sc0 sc1" : "=v"(r) : "v"(p));
  return r;
}
__device__ __forceinline__ i32x2 ldg_n8(const void* p) {
  i32x2 r;
  asm volatile("global_load_dwordx2 %0, %1, off" : "=v"(r) : "v"(p));
  return r;
}
__device__ __forceinline__ int ldg_n4(const void* p) {
  int r;
  asm volatile("global_load_dword %0, %1, off" : "=v"(r) : "v"(p));
  return r;
}
__device__ __forceinline__ void stg_c4(void* p, int v) {
  asm volatile("global_store_dword %0, %1, off sc0 sc1"
               :: "v"(p), "v"(v) : "memory");
}
__device__ __forceinline__ void stg_c8(void* p, i32x2 v) {  // 8B tagged unit
  asm volatile("global_store_dwordx2 %0, %1, off sc0 sc1"
               :: "v"(p), "v"(v) : "memory");
}
__device__ __forceinline__ void stg_n8(void* p, i32x2 v) {
  asm volatile("global_store_dwordx2 %0, %1, off"
               :: "v"(p), "v"(v) : "memory");
}
__device__ __forceinline__ void waitcnt_vm0() {
  asm volatile("s_waitcnt vmcnt(0)" ::: "memory");
}
#define HOLD4(x) asm volatile("" : "+v"(x))
#define HOLD2(x) asm volatile("" : "+v"(x))
#define HOLDI(x) asm volatile("" : "+v"(x))

// fast transcendentals (inf-safe at saturation; err ~1e-6 << 2^-8 bf16 noise)
__device__ __forceinline__ float sigm_f(float x) {
  return __fdividef(1.f, 1.f + __expf(-x));
}
__device__ __forceinline__ float tanh_f(float x) {
  return 1.f - __fdividef(2.f, __expf(2.f * x) + 1.f);
}

// ---- tagged-h poll: load 12 fragments (3 i-slots x 4 rt x 2 units), spin
// until every unit's tag == t. Sticky watchdog: after ~1M failed rounds set
// dead=1 and stop polling forever (turns a protocol hang into a visible
// wrong-answer instead of a wedged GPU). Success path cost: one dead test. ----
#define TPOLL(ha, I0)                                                          \
  if (!dead) {                                                                 \
    int spins = 0;                                                             \
    for (;;) {                                                                 \
      _Pragma("unroll") for (int ii = 0; ii < 3; ++ii)                         \
        _Pragma("unroll") for (int rt = 0; rt < 4; ++rt)                       \
          _Pragma("unroll") for (int u = 0; u < 2; ++u)                        \
            ha[ii][rt][u] = ldg_c16(hb + (size_t)((rt * 16 + l15) * 384 +      \
                             (wave * 6 + (I0) + ii) * 16 + quad * 4 + u * 2) * 8);\
      waitcnt_vm0();                                                           \
      int okv = 1;                                                             \
      _Pragma("unroll") for (int ii = 0; ii < 3; ++ii)                         \
        _Pragma("unroll") for (int rt = 0; rt < 4; ++rt)                       \
          _Pragma("unroll") for (int u = 0; u < 2; ++u) {                      \
            HOLD4(ha[ii][rt][u]);                                              \
            okv &= (ha[ii][rt][u][1] == t) & (ha[ii][rt][u][3] == t);          \
          }                                                                    \
      if (__all(okv)) break;                                                   \
      if (++spins > (1 << 20)) { dead = 1; break; }                            \
      __builtin_amdgcn_s_sleep(1);                                             \
    }                                                                          \
  }

// ---- MFMA over a polled half: extract data dwords, 8 MFMAs per i-slot ----
#define TMFMA(ha, I0)                                                          \
  _Pragma("unroll") for (int ii = 0; ii < 3; ++ii) {                           \
    const int kc = 96 + (wave * 6 + (I0) + ii) * 4 + quad;                     \
    bf16x8 b0 = *(const bf16x8*)&Bl2[(size_t)(kc * 32 + l15) * 8];             \
    bf16x8 b1 = *(const bf16x8*)&Bl2[(size_t)(kc * 32 + 16 + l15) * 8];        \
    _Pragma("unroll") for (int rt = 0; rt < 4; ++rt) {                         \
      i32x4 dv;                                                                \
      dv[0] = ha[ii][rt][0][0]; dv[1] = ha[ii][rt][0][2];                      \
      dv[2] = ha[ii][rt][1][0]; dv[3] = ha[ii][rt][1][2];                      \
      bf16x8 av = __builtin_bit_cast(bf16x8, dv);                              \
      acc[rt][0] = __builtin_amdgcn_mfma_f32_16x16x32_bf16(av, b0, acc[rt][0], 0, 0, 0); \
      acc[rt][1] = __builtin_amdgcn_mfma_f32_16x16x32_bf16(av, b1, acc[rt][1], 0, 0, 0); \
    } }

// legacy h-phase step (modes 0/1): wait 4 more loads, 8 MFMAs.
#define HSTEP(i, VMS)                                                         \
  asm volatile("s_waitcnt vmcnt(" VMS ")");                                   \
  HOLD4(hr[i][0]); HOLD4(hr[i][1]); HOLD4(hr[i][2]); HOLD4(hr[i][3]);         \
  { const int kc = 96 + (wave * 6 + (i)) * 4 + quad;                          \
    bf16x8 b0 = *(const bf16x8*)&Bl2[(size_t)(kc * 32 + l15) * 8];            \
    bf16x8 b1 = *(const bf16x8*)&Bl2[(size_t)(kc * 32 + 16 + l15) * 8];       \
    _Pragma("unroll")                                                         \
    for (int rt = 0; rt < 4; ++rt) {                                          \
      bf16x8 av = __builtin_bit_cast(bf16x8, hr[i][rt]);                      \
      acc[rt][0] = __builtin_amdgcn_mfma_f32_16x16x32_bf16(av, b0, acc[rt][0], 0, 0, 0); \
      acc[rt][1] = __builtin_amdgcn_mfma_f32_16x16x32_bf16(av, b1, acc[rt][1], 0, 0, 0); \
    } }

// ---------------- persistent recurrent kernel ----------------
// MODE: 0 = xf, 1 = xb (legacy flag protocol), 2 = gx f32, 3 = gx f16 (tagged)
template <int MODE>
__global__ __launch_bounds__(256, 1)
void k_lstm(const __bf16* __restrict__ xb, const float* __restrict__ xf,
            const void* __restrict__ gxv,
            const __bf16* __restrict__ WT, const float* __restrict__ kT,
            const float* __restrict__ bias, const float* __restrict__ wpeep,
            void* h0buf, void* h1buf, float* __restrict__ out, int* flags) {
  const int j = blockIdx.x, d0 = j * ND;
  const int tid = threadIdx.x;
  const int wave = tid >> 6, lane = tid & 63;
  const int quad = lane >> 4, l15 = lane & 15;

  __shared__ __align__(16) __bf16 Bl2[192 * 32 * 8];
  __shared__ float gacc2[4][32][68];

  // ---- preload B slice into LDS (once); gx modes use only the U half ----
  for (int idx = tid + (MODE >= 2 ? 3072 : 0); idx < 6144; idx += 256) {
    int c = idx & 31, kc = idx >> 5;
    int n = (c >> 3) * 768 + d0 + (c & 7);
    *(bf16x8*)&Bl2[(size_t)idx * 8] = *(const bf16x8*)&WT[(size_t)n * 1536 + kc * 8];
  }

  // elementwise mapping: thread = (batch bb, dim-pair dq)
  const int dq = tid & 3, bb = tid >> 2;
  const int ed0 = d0 + dq * 2;
  const f32x2 bi2  = *(const f32x2*)&bias[ed0];
  const f32x2 bf2  = *(const f32x2*)&bias[768 + ed0];
  const f32x2 bo2  = *(const f32x2*)&bias[1536 + ed0];
  const f32x2 bc2  = *(const f32x2*)&bias[2304 + ed0];
  const f32x2 wpi2 = *(const f32x2*)&wpeep[ed0];
  const f32x2 wpf2 = *(const f32x2*)&wpeep[768 + ed0];
  const f32x2 wpo2 = *(const f32x2*)&wpeep[1536 + ed0];

  // legacy poll set (modes 0/1)
  const int fid0 = wave * 96 + lane;
  const int fid1 = wave * 96 + 64 + (lane & 31);
  const int* fp0 = flags + fid0 * 16;
  const int* fp1 = flags + fid1 * 16;

  f32x2 creg; creg[0] = 0.f; creg[1] = 0.f;
  f32x2 hreg; hreg[0] = 0.f; hreg[1] = 0.f;

  int dead = 0;  // watchdog state (tagged path)

  __syncthreads();

  for (int t = 0; t < TDIM; ++t) {
    f32x4 acc[4][2];
#pragma unroll
    for (int rt = 0; rt < 4; ++rt) {
      acc[rt][0] = (f32x4){0.f, 0.f, 0.f, 0.f};
      acc[rt][1] = (f32x4){0.f, 0.f, 0.f, 0.f};
    }

    // ---- prefetches (BEFORE any long wait; drained by first poll round) ----
    i32x2 ktraw = ldg_n8(kT + (size_t)t * 768 + ed0);
    i32x2 gx8[4];
    int   gx4[4];
    if constexpr (MODE == 2) {
#pragma unroll
      for (int g = 0; g < 4; ++g)
        gx8[g] = ldg_n8((const float*)gxv + ((size_t)(t * 64 + bb)) * 3072 + g * 768 + ed0);
    } else if constexpr (MODE == 3) {
#pragma unroll
      for (int g = 0; g < 4; ++g)
        gx4[g] = ldg_n4((const _Float16*)gxv + ((size_t)(t * 64 + bb)) * 3072 + g * 768 + ed0);
    }

    if constexpr (MODE >= 2) {
      // ================== tagged h-exchange path ==================
      const char* hb = (const char*)((t & 1) ? h1buf : h0buf);
      char*       hn = (char*)((t & 1) ? h0buf : h1buf);

      // poll+load half A (i=0..2; 12 producer blocks), then MFMA
      i32x4 ha[3][4][2];
      TPOLL(ha, 0)
      HOLD2(ktraw);   // drained by round-1 vmcnt(0)
      if constexpr (MODE == 2) { HOLD2(gx8[0]); HOLD2(gx8[1]); HOLD2(gx8[2]); HOLD2(gx8[3]); }
      if constexpr (MODE == 3) { HOLDI(gx4[0]); HOLDI(gx4[1]); HOLDI(gx4[2]); HOLDI(gx4[3]); }
      TMFMA(ha, 0)
      // poll+load half B (i=3..5; other 12 producer blocks), then MFMA
      TPOLL(ha, 3)
      TMFMA(ha, 3)

      // ---- partials -> LDS (col-major, b128) ----
#pragma unroll
      for (int rt = 0; rt < 4; ++rt) {
        *(f32x4*)&gacc2[wave][l15][rt * 16 + quad * 4]      = acc[rt][0];
        *(f32x4*)&gacc2[wave][16 + l15][rt * 16 + quad * 4] = acc[rt][1];
      }
      __syncthreads();

      f32x2 kt2 = __builtin_bit_cast(f32x2, ktraw);
      float gs[2][4];
#pragma unroll
      for (int dd = 0; dd < 2; ++dd)
#pragma unroll
        for (int g = 0; g < 4; ++g) {
          float s = 0.f;
#pragma unroll
          for (int w = 0; w < 4; ++w) s += gacc2[w][g * 8 + dq * 2 + dd][bb];
          if constexpr (MODE == 2)
            s += __builtin_bit_cast(f32x2, gx8[g])[dd];
          else
            s += (float)__builtin_bit_cast(f16x2, gx4[g])[dd];
          gs[dd][g] = s;
        }
      __syncthreads();   // gacc2 reads done; all waves past polls

      f32x2 cnv, hnv;
#pragma unroll
      for (int dd = 0; dd < 2; ++dd) {
        float c_prev = creg[dd], h_prev = hreg[dd], kt = kt2[dd];
        float gi = gs[dd][0] + bi2[dd] + wpi2[dd] * c_prev;
        float gf = gs[dd][1] + bf2[dd] + wpf2[dd] * c_prev;
        float go = gs[dd][2] + bo2[dd] + wpo2[dd] * c_prev;
        float gc = gs[dd][3] + bc2[dd];
        float iv = sigm_f(gi);
        float fv = sigm_f(gf);
        float ov = sigm_f(go);
        float cp = fv * c_prev + iv * tanh_f(gc);
        float cn = kt * cp + (1.f - kt) * c_prev;
        float hp = tanh_f(cp) * ov;
        float hn2 = kt * hp + (1.f - kt) * h_prev;
        cnv[dd] = cn; hnv[dd] = hn2;
      }
      creg = cnv; hreg = hnv;

      // tagged h-store: single 8B {2xbf16, t+1}. No drain, no flag.
      __bf16 h0 = (__bf16)hnv[0], h1 = (__bf16)hnv[1];
      unsigned hu = (unsigned)__builtin_bit_cast(unsigned short, h0) |
                    ((unsigned)__builtin_bit_cast(unsigned short, h1) << 16);
      i32x2 unit; unit[0] = (int)hu; unit[1] = t + 1;
      stg_c8(hn + (size_t)(bb * 384 + j * 4 + dq) * 8, unit);
      f32x2 ov2; ov2[0] = hnv[0]; ov2[1] = hnv[1];
      stg_n8(out + ((size_t)bb * 512 + t) * 768 + ed0, __builtin_bit_cast(i32x2, ov2));
      // outstanding stores drain under next step's poll vmcnt(0).
    } else {
      // ================== legacy flag-protocol path (modes 0/1) ==================
      const __bf16* hcur = (const __bf16*)((t & 1) ? h1buf : h0buf);
      __bf16* hnxt = (__bf16*)((t & 1) ? h0buf : h1buf);

#pragma unroll
      for (int i = 0; i < 6; ++i) {
        const int kk = (wave * 6 + i) * 32 + quad * 8;
        const int kc = kk >> 3;
        bf16x8 a[4];
        if constexpr (MODE == 1) {
#pragma unroll
          for (int rt = 0; rt < 4; ++rt)
            a[rt] = *(const bf16x8*)(xb + ((size_t)(t * 64 + rt * 16 + l15)) * 768 + kk);
        } else {
#pragma unroll
          for (int rt = 0; rt < 4; ++rt)
#pragma unroll
            for (int q = 0; q < 8; ++q)
              a[rt][q] = (__bf16)xf[((size_t)(rt * 16 + l15) * 512 + t) * 768 + kk + q];
        }
        bf16x8 b0 = *(const bf16x8*)&Bl2[(size_t)(kc * 32 + l15) * 8];
        bf16x8 b1 = *(const bf16x8*)&Bl2[(size_t)(kc * 32 + 16 + l15) * 8];
#pragma unroll
        for (int rt = 0; rt < 4; ++rt) {
          acc[rt][0] = __builtin_amdgcn_mfma_f32_16x16x32_bf16(a[rt], b0, acc[rt][0], 0, 0, 0);
          acc[rt][1] = __builtin_amdgcn_mfma_f32_16x16x32_bf16(a[rt], b1, acc[rt][1], 0, 0, 0);
        }
      }

      for (;;) {
        int v0, v1;
        asm volatile("global_load_dword %0, %2, off sc0 sc1\n\t"
                     "global_load_dword %1, %3, off sc0 sc1\n\t"
                     "s_waitcnt vmcnt(0)"
                     : "=v"(v0), "=v"(v1) : "v"(fp0), "v"(fp1) : "memory");
        if (__all(v0 >= t && v1 >= t)) break;
        __builtin_amdgcn_s_sleep(1);
      }
      HOLD2(ktraw);

      i32x4 hr[6][4];
#pragma unroll
      for (int i = 0; i < 6; ++i) {
        const int hoff = (wave * 6 + i) * 32 + quad * 8;
#pragma unroll
        for (int rt = 0; rt < 4; ++rt)
          hr[i][rt] = ldg_c16(hcur + (size_t)(rt * 16 + l15) * 768 + hoff);
      }
      HSTEP(0, "20")
      HSTEP(1, "16")
      HSTEP(2, "12")
      HSTEP(3, "8")
      HSTEP(4, "4")
      HSTEP(5, "0")

#pragma unroll
      for (int rt = 0; rt < 4; ++rt) {
        *(f32x4*)&gacc2[wave][l15][rt * 16 + quad * 4]      = acc[rt][0];
        *(f32x4*)&gacc2[wave][16 + l15][rt * 16 + quad * 4] = acc[rt][1];
      }
      __syncthreads();

      f32x2 kt2 = __builtin_bit_cast(f32x2, ktraw);
      float gs[2][4];
#pragma unroll
      for (int dd = 0; dd < 2; ++dd)
#pragma unroll
        for (int g = 0; g < 4; ++g) {
          float s = 0.f;
#pragma unroll
          for (int w = 0; w < 4; ++w) s += gacc2[w][g * 8 + dq * 2 + dd][bb];
          gs[dd][g] = s;
        }
      __syncthreads();

      f32x2 cnv, hnv;
#pragma unroll
      for (int dd = 0; dd < 2; ++dd) {
        float c_prev = creg[dd], h_prev = hreg[dd], kt = kt2[dd];
        float gi = gs[dd][0] + bi2[dd] + wpi2[dd] * c_prev;
        float gf = gs[dd][1] + bf2[dd] + wpf2[dd] * c_prev;
        float go = gs[dd][2] + bo2[dd] + wpo2[dd] * c_prev;
        float gc = gs[dd][3] + bc2[dd];
        float iv = sigm_f(gi);
        float fv = sigm_f(gf);
        float ov = sigm_f(go);
        float cp = fv * c_prev + iv * tanh_f(gc);
        float cn = kt * cp + (1.f - kt) * c_prev;
        float hp = tanh_f(cp) * ov;
        float hn2 = kt * hp + (1.f - kt) * h_prev;
        cnv[dd] = cn; hnv[dd] = hn2;
      }
      creg = cnv; hreg = hnv;

      __bf16 h0 = (__bf16)hnv[0], h1 = (__bf16)hnv[1];
      unsigned hu = (unsigned)__builtin_bit_cast(unsigned short, h0) |
                    ((unsigned)__builtin_bit_cast(unsigned short, h1) << 16);
      stg_c4(hnxt + (size_t)bb * 768 + ed0, (int)hu);
      waitcnt_vm0();
      if (lane == 0) stg_c4(flags + (j * 4 + wave) * 16, t + 1);
      f32x2 ov2; ov2[0] = hnv[0]; ov2[1] = hnv[1];
      stg_n8(out + ((size_t)bb * 512 + t) * 768 + ed0, __builtin_bit_cast(i32x2, ov2));
    }
  }
}

// ---------------- launch ----------------
extern "C" void kernel_launch(void* const* d_in, const int* in_sizes, int n_in,
                              void* d_out, int out_size, void* d_ws, size_t ws_size,
                              hipStream_t stream) {
  const float* x     = (const float*)d_in[0];
  const float* W     = (const float*)d_in[1];
  const float* U     = (const float*)d_in[2];
  const float* bias  = (const float*)d_in[3];
  const float* wpeep = (const float*)d_in[4];
  const float* tau   = (const float*)d_in[5];
  const float* shift = (const float*)d_in[6];
  float* out = (float*)d_out;
  char* ws = (char*)d_ws;

  int*    flags = (int*)(ws + OFF_FLAGS);
  void*   hb0 = (void*)(ws + OFF_HBUF0);
  void*   hb1 = (void*)(ws + OFF_HBUF1);
  float*  kT  = (float*)(ws + OFF_KTAB);
  __bf16* WT  = (__bf16*)(ws + OFF_WT);
  __bf16* xb  = (__bf16*)(ws + OFF_XB);
  void*   gxp = (void*)(ws + OFF_GX);

  int mode;
  if      (ws_size >= WS_NEED_GXF32) mode = 2;
  else if (ws_size >= WS_NEED_GXF16) mode = 3;
  else if (ws_size >= WS_NEED_FULL)  mode = 1;
  else                               mode = 0;

  hipMemsetAsync(ws, 0, OFF_KTAB, stream);  // flags + both tagged h buffers = 0
  k_wcomb<<<48 * 96, 256, 0, stream>>>(W, U, WT);
  k_ktab<<<(512 * 768) / 256, 256, 0, stream>>>(tau, shift, kT);

  if (mode == 2) {
    k_xgemm<0><<<256 * 24, 256, 0, stream>>>(x, WT, gxp);
    k_lstm<2><<<G_BLOCKS, 256, 0, stream>>>(nullptr, x, gxp, WT, kT, bias, wpeep,
                                            hb0, hb1, out, flags);
  } else if (mode == 3) {
    k_xgemm<1><<<256 * 24, 256, 0, stream>>>(x, WT, gxp);
    k_lstm<3><<<G_BLOCKS, 256, 0, stream>>>(nullptr, x, gxp, WT, kT, bias, wpeep,
                                            hb0, hb1, out, flags);
  } else if (mode == 1) {
    k_xb<<<(512 * 64 * 768) / 256, 256, 0, stream>>>(x, xb);
    k_lstm<1><<<G_BLOCKS, 256, 0, stream>>>(xb, x, nullptr, WT, kT, bias, wpeep,
                                            hb0, hb1, out, flags);
  } else {
    k_lstm<0><<<G_BLOCKS, 256, 0, stream>>>(nullptr, x, nullptr, WT, kT, bias, wpeep,
                                            hb0, hb1, out, flags);
  }
}

// Round 9
// 3272.910 us; speedup vs baseline: 1.5426x; 1.5426x over previous
//
#include <hip/hip_runtime.h>
#include <math.h>

// PhasedLSTM: B=64, T=512, H=768. fp32 in/out.
// Persistent kernel, distributed per-wave flag barrier per timestep.
// R9 = R3-measured structure (best: 2946us) + fast transcendentals ONLY.
//   R3 structure: gx tiers (f32 414MB / f16 213MB; k_xgemm reads x directly),
//   R4-proven poll (4 flag lines/block, 96 lines/wave, 2 loads/round),
//   wave-granular flag store after the wave's own vmcnt drain, kt/gx
//   prefetch BEFORE the poll (hidden under poll RT, drained by its vmcnt0).
//   R8 post-mortem: tagged-h (poll-the-data) regressed 2946->4544 -- retry
//   granule was 24x16B coherent reloads/round vs 2x4B here. Reverted.
//   This round's single change: libm expf/tanhf -> __expf/__fdividef forms
//   (numerics validated in R4/R8 runs: absmax unchanged 0.00390625).
//   Modes: 0=xf, 1=xb, 2=gx f32, 3=gx f16.

#define HDIM 768
#define BDIM 64
#define TDIM 512
#define G_BLOCKS 96
#define ND 8   // hidden dims per block (768/96)

typedef float f32x4 __attribute__((ext_vector_type(4)));
typedef float f32x2 __attribute__((ext_vector_type(2)));
typedef __bf16 bf16x8 __attribute__((ext_vector_type(8)));
typedef _Float16 f16x2 __attribute__((ext_vector_type(2)));
typedef int i32x4 __attribute__((ext_vector_type(4)));
typedef int i32x2 __attribute__((ext_vector_type(2)));

// workspace layout (bytes)
#define OFF_FLAGS 0                                     // 384 x 64B lines
#define OFF_HBUF0 24576
#define OFF_HBUF1 (24576 + 98304)
#define OFF_KTAB  (24576 + 2*98304)                     // 221184
#define OFF_WT    (OFF_KTAB + (size_t)512*768*4)        // + 1.5MB
#define OFF_XB    (OFF_WT + (size_t)3072*1536*2)        // + 9.4MB = 11231232
#define WS_NEED_FULL (OFF_XB + (size_t)512*64*768*2)    // ~61.6MB (mode 1)
#define OFF_GX    OFF_XB                                // gx replaces xb
#define WS_NEED_GXF32 (OFF_GX + (size_t)32768*3072*4)   // ~413.9MB
#define WS_NEED_GXF16 (OFF_GX + (size_t)32768*3072*2)   // ~212.6MB

// ---------------- prep kernels ----------------

__global__ void k_wcomb(const float* __restrict__ W, const float* __restrict__ U,
                        __bf16* __restrict__ WT) {
  __shared__ __bf16 tile[32][33];
  int tk = blockIdx.x % 48;   // k tile (1536/32)
  int tn = blockIdx.x / 48;   // n tile (3072/32)
  int tx = threadIdx.x & 31, ty = threadIdx.x >> 5; // 32 x 8
  int k0 = tk * 32, n0 = tn * 32;
#pragma unroll
  for (int i = 0; i < 4; ++i) {
    int k = k0 + ty + 8 * i;
    int n = n0 + tx;
    const float* M = (k < 768) ? W : U;
    int r = (k < 768) ? k : k - 768;
    float v;
    if (n < 2304)
      v = M[(size_t)r * 3072 + n] + M[(size_t)(768 + r) * 3072 + n] +
          M[(size_t)(1536 + r) * 3072 + n];
    else
      v = M[(size_t)(2304 + r) * 3072 + n];
    tile[ty + 8 * i][tx] = (__bf16)v;
  }
  __syncthreads();
#pragma unroll
  for (int i = 0; i < 4; ++i) {
    int n = n0 + ty + 8 * i;
    int k = k0 + tx;
    WT[(size_t)n * 1536 + k] = tile[tx][ty + 8 * i];
  }
}

__global__ void k_ktab(const float* __restrict__ tau, const float* __restrict__ shift,
                       float* __restrict__ kT) {
  int idx = blockIdx.x * 256 + threadIdx.x;  // t*768 + d
  int d = idx % 768, t = idx / 768;
  float bb = tau[d];
  float a = (float)t - shift[d];
  const float PI = 3.14159265358979323846f;
  float fm = bb / PI * atanf(tanf(PI * (a / bb - 0.5f))) + bb * 0.5f;
  float phi = fm / (bb + 1e-8f);
  float kv;
  if (phi < 0.5f * 0.05f)      kv = 2.0f * phi / 0.05f;
  else if (phi < 0.05f)        kv = 2.0f - 2.0f * phi / 0.05f;
  else                         kv = 0.001f * phi;
  kT[idx] = kv;
}

__global__ void k_xb(const float* __restrict__ x, __bf16* __restrict__ xb) {
  int idx = blockIdx.x * 256 + threadIdx.x;  // (t*64+b)*768 + k
  int k = idx % 768;
  int tb = idx / 768;
  int b = tb % 64, t = tb / 64;
  xb[idx] = (__bf16)x[((size_t)b * 512 + t) * 768 + k];
}

// gx[m][n] = sum_{k<768} x_bf16[m][k] * WT[n][k], m=t*64+b, n in [0,3072)
// 128x128 tile, BK=64, reg-staged LDS with XOR swizzle (byte ^= (row&7)<<4).
template <int F16OUT>
__global__ __launch_bounds__(256, 2)
void k_xgemm(const float* __restrict__ x, const __bf16* __restrict__ Wt,
             void* __restrict__ Cv) {
  __shared__ __align__(16) unsigned char AsB[128 * 128];
  __shared__ __align__(16) unsigned char BsB[128 * 128];
  const int tid = threadIdx.x;
  const int wave = tid >> 6, lane = tid & 63;
  const int quad = lane >> 4, l15 = lane & 15;
  const int wr = wave >> 1, wc = wave & 1;
  const int mt = blockIdx.x / 24, nt = blockIdx.x % 24;
  const int m0 = mt * 128, n0 = nt * 128;

  f32x4 acc[4][4];
#pragma unroll
  for (int i = 0; i < 4; ++i)
#pragma unroll
    for (int jj = 0; jj < 4; ++jj) acc[i][jj] = (f32x4){0.f, 0.f, 0.f, 0.f};

  for (int kt = 0; kt < 12; ++kt) {
#pragma unroll
    for (int s0 = 0; s0 < 4; ++s0) {
      int s = s0 * 256 + tid;
      int row = s >> 3, part = s & 7;
      int sw = (row & 7) << 4;
      int m = m0 + row;
      const float* ap = x + ((size_t)(m & 63) * 512 + (m >> 6)) * 768 + kt * 64 + part * 8;
      f32x4 a0 = *(const f32x4*)ap;
      f32x4 a1 = *(const f32x4*)(ap + 4);
      bf16x8 av;
#pragma unroll
      for (int q = 0; q < 4; ++q) { av[q] = (__bf16)a0[q]; av[q + 4] = (__bf16)a1[q]; }
      *(bf16x8*)&AsB[row * 128 + ((part * 16) ^ sw)] = av;
      i32x4 vb = *(const i32x4*)((const unsigned char*)Wt +
                                 (size_t)(n0 + row) * 3072 + kt * 128 + part * 16);
      *(i32x4*)&BsB[row * 128 + ((part * 16) ^ sw)] = vb;
    }
    __syncthreads();
#pragma unroll
    for (int ks = 0; ks < 2; ++ks) {
      const int cb = (ks * 32 + quad * 8) * 2;
      bf16x8 af[4], bfr[4];
#pragma unroll
      for (int f = 0; f < 4; ++f) {
        int ar = wr * 64 + f * 16 + l15;
        af[f] = *(const bf16x8*)&AsB[ar * 128 + (cb ^ ((ar & 7) << 4))];
        int br = wc * 64 + f * 16 + l15;
        bfr[f] = *(const bf16x8*)&BsB[br * 128 + (cb ^ ((br & 7) << 4))];
      }
#pragma unroll
      for (int fm = 0; fm < 4; ++fm)
#pragma unroll
        for (int fn = 0; fn < 4; ++fn)
          acc[fm][fn] = __builtin_amdgcn_mfma_f32_16x16x32_bf16(af[fm], bfr[fn],
                                                                acc[fm][fn], 0, 0, 0);
    }
    __syncthreads();
  }
#pragma unroll
  for (int fm = 0; fm < 4; ++fm) {
    int m = m0 + wr * 64 + fm * 16 + quad * 4;
#pragma unroll
    for (int fn = 0; fn < 4; ++fn) {
      int n = n0 + wc * 64 + fn * 16 + l15;
#pragma unroll
      for (int r = 0; r < 4; ++r) {
        if constexpr (F16OUT)
          ((_Float16*)Cv)[(size_t)(m + r) * 3072 + n] = (_Float16)acc[fm][fn][r];
        else
          ((float*)Cv)[(size_t)(m + r) * 3072 + n] = acc[fm][fn][r];
      }
    }
  }
}

// ---------------- asm memory helpers ----------------
__device__ __forceinline__ i32x4 ldg_c16(const void* p) {
  i32x4 r;
  asm volatile("global_load_dwordx4 %0, %1, off sc0 sc1" : "=v"(r) : "v"(p));
  return r;
}
__device__ __forceinline__ i32x2 ldg_n8(const void* p) {
  i32x2 r;
  asm volatile("global_load_dwordx2 %0, %1, off" : "=v"(r) : "v"(p));
  return r;
}
__device__ __forceinline__ int ldg_n4(const void* p) {
  int r;
  asm volatile("global_load_dword %0, %1, off" : "=v"(r) : "v"(p));
  return r;
}
__device__ __forceinline__ void stg_c4(void* p, int v) {
  asm volatile("global_store_dword %0, %1, off sc0 sc1"
               :: "v"(p), "v"(v) : "memory");
}
__device__ __forceinline__ void stg_n8(void* p, i32x2 v) {
  asm volatile("global_store_dwordx2 %0, %1, off"
               :: "v"(p), "v"(v) : "memory");
}
__device__ __forceinline__ void waitcnt_vm0() {
  asm volatile("s_waitcnt vmcnt(0)" ::: "memory");
}
#define HOLD4(x) asm volatile("" : "+v"(x))
#define HOLD2(x) asm volatile("" : "+v"(x))
#define HOLDI(x) asm volatile("" : "+v"(x))

// fast transcendentals (inf-safe at saturation; err ~1e-6 << 2^-8 bf16 noise;
// numerics validated on-HW in R4/R8 runs: absmax unchanged)
__device__ __forceinline__ float sigm_f(float x) {
  return __fdividef(1.f, 1.f + __expf(-x));
}
__device__ __forceinline__ float tanh_f(float x) {
  return 1.f - __fdividef(2.f, __expf(2.f * x) + 1.f);
}

// h-phase step: wait for 4 more loads, run 8 MFMAs on them.
#define HSTEP(i, VMS)                                                         \
  asm volatile("s_waitcnt vmcnt(" VMS ")");                                   \
  HOLD4(hr[i][0]); HOLD4(hr[i][1]); HOLD4(hr[i][2]); HOLD4(hr[i][3]);         \
  { const int kc = 96 + (wave * 6 + (i)) * 4 + quad;                          \
    bf16x8 b0 = *(const bf16x8*)&Bl2[(size_t)(kc * 32 + l15) * 8];            \
    bf16x8 b1 = *(const bf16x8*)&Bl2[(size_t)(kc * 32 + 16 + l15) * 8];       \
    _Pragma("unroll")                                                         \
    for (int rt = 0; rt < 4; ++rt) {                                          \
      bf16x8 av = __builtin_bit_cast(bf16x8, hr[i][rt]);                      \
      acc[rt][0] = __builtin_amdgcn_mfma_f32_16x16x32_bf16(av, b0, acc[rt][0], 0, 0, 0); \
      acc[rt][1] = __builtin_amdgcn_mfma_f32_16x16x32_bf16(av, b1, acc[rt][1], 0, 0, 0); \
    } }

// ---------------- persistent recurrent kernel ----------------
// MODE: 0 = xf (f32 x, scalar), 1 = xb (bf16 x, in-loop x-phase),
//       2 = gx f32 (precomputed x@W), 3 = gx f16
template <int MODE>
__global__ __launch_bounds__(256, 1)
void k_lstm(const __bf16* __restrict__ xb, const float* __restrict__ xf,
            const void* __restrict__ gxv,
            const __bf16* __restrict__ WT, const float* __restrict__ kT,
            const float* __restrict__ bias, const float* __restrict__ wpeep,
            __bf16* h0buf, __bf16* h1buf, float* __restrict__ out, int* flags) {
  const int j = blockIdx.x, d0 = j * ND;
  const int tid = threadIdx.x;
  const int wave = tid >> 6, lane = tid & 63;
  const int quad = lane >> 4, l15 = lane & 15;

  // LDS: B slice chunk-major (kc-chunk of 8 k, 32 cols, 16B each);
  // gacc col-major (b128 writes).
  __shared__ __align__(16) __bf16 Bl2[192 * 32 * 8];
  __shared__ float gacc2[4][32][68];

  // ---- preload B slice into LDS (once) ----
  for (int idx = tid; idx < 6144; idx += 256) {  // idx = kc*32 + c
    int c = idx & 31, kc = idx >> 5;
    int n = (c >> 3) * 768 + d0 + (c & 7);
    *(bf16x8*)&Bl2[(size_t)idx * 8] = *(const bf16x8*)&WT[(size_t)n * 1536 + kc * 8];
  }

  // elementwise mapping: thread = (batch bb, dim-pair dq)
  const int dq = tid & 3, bb = tid >> 2;
  const int ed0 = d0 + dq * 2;
  const f32x2 bi2  = *(const f32x2*)&bias[ed0];
  const f32x2 bf2  = *(const f32x2*)&bias[768 + ed0];
  const f32x2 bo2  = *(const f32x2*)&bias[1536 + ed0];
  const f32x2 bc2  = *(const f32x2*)&bias[2304 + ed0];
  const f32x2 wpi2 = *(const f32x2*)&wpeep[ed0];
  const f32x2 wpf2 = *(const f32x2*)&wpeep[768 + ed0];
  const f32x2 wpo2 = *(const f32x2*)&wpeep[1536 + ed0];

  // poll set (R4-proven): wave w consumes dims [w*192,(w+1)*192) = blocks
  // [w*24,(w+1)*24); each block has 4 wave-granular flag lines -> ids
  // [w*96,(w+1)*96). Two loads cover 96 lines (64 + 32 lanes).
  const int fid0 = wave * 96 + lane;
  const int fid1 = wave * 96 + 64 + (lane & 31);
  const int* fp0 = flags + fid0 * 16;
  const int* fp1 = flags + fid1 * 16;

  // c/h state in registers (thread-private by construction)
  f32x2 creg; creg[0] = 0.f; creg[1] = 0.f;
  f32x2 hreg; hreg[0] = 0.f; hreg[1] = 0.f;

  __syncthreads();

  for (int t = 0; t < TDIM; ++t) {
    const __bf16* hcur = (t & 1) ? h1buf : h0buf;
    __bf16* hnxt = (t & 1) ? h0buf : h1buf;

    // ---- prefetches (asm; drained by poll's vmcnt0) ----
    i32x2 ktraw = ldg_n8(kT + (size_t)t * 768 + ed0);
    i32x2 gx8[4];
    int   gx4[4];
    if constexpr (MODE == 2) {
#pragma unroll
      for (int g = 0; g < 4; ++g)
        gx8[g] = ldg_n8((const float*)gxv + ((size_t)(t * 64 + bb)) * 3072 + g * 768 + ed0);
    } else if constexpr (MODE == 3) {
#pragma unroll
      for (int g = 0; g < 4; ++g)
        gx4[g] = ldg_n4((const _Float16*)gxv + ((size_t)(t * 64 + bb)) * 3072 + g * 768 + ed0);
    }

    f32x4 acc[4][2];
#pragma unroll
    for (int rt = 0; rt < 4; ++rt) {
      acc[rt][0] = (f32x4){0.f, 0.f, 0.f, 0.f};
      acc[rt][1] = (f32x4){0.f, 0.f, 0.f, 0.f};
    }

    // ---- x-phase (only modes 0/1) ----
    if constexpr (MODE < 2) {
#pragma unroll
      for (int i = 0; i < 6; ++i) {
        const int kk = (wave * 6 + i) * 32 + quad * 8;   // k in [0,768)
        const int kc = kk >> 3;
        bf16x8 a[4];
        if constexpr (MODE == 1) {
#pragma unroll
          for (int rt = 0; rt < 4; ++rt)
            a[rt] = *(const bf16x8*)(xb + ((size_t)(t * 64 + rt * 16 + l15)) * 768 + kk);
        } else {
#pragma unroll
          for (int rt = 0; rt < 4; ++rt)
#pragma unroll
            for (int q = 0; q < 8; ++q)
              a[rt][q] = (__bf16)xf[((size_t)(rt * 16 + l15) * 512 + t) * 768 + kk + q];
        }
        bf16x8 b0 = *(const bf16x8*)&Bl2[(size_t)(kc * 32 + l15) * 8];
        bf16x8 b1 = *(const bf16x8*)&Bl2[(size_t)(kc * 32 + 16 + l15) * 8];
#pragma unroll
        for (int rt = 0; rt < 4; ++rt) {
          acc[rt][0] = __builtin_amdgcn_mfma_f32_16x16x32_bf16(a[rt], b0, acc[rt][0], 0, 0, 0);
          acc[rt][1] = __builtin_amdgcn_mfma_f32_16x16x32_bf16(a[rt], b1, acc[rt][1], 0, 0, 0);
        }
      }
    }

    // ---- per-wave poll: my producers' h_t visible? (2 loads, 96 lines) ----
    for (;;) {
      int v0, v1;
      asm volatile("global_load_dword %0, %2, off sc0 sc1\n\t"
                   "global_load_dword %1, %3, off sc0 sc1\n\t"
                   "s_waitcnt vmcnt(0)"
                   : "=v"(v0), "=v"(v1) : "v"(fp0), "v"(fp1) : "memory");
      if (__all(v0 >= t && v1 >= t)) break;
      __builtin_amdgcn_s_sleep(1);
    }
    HOLD2(ktraw);
    if constexpr (MODE == 2) { HOLD2(gx8[0]); HOLD2(gx8[1]); HOLD2(gx8[2]); HOLD2(gx8[3]); }
    if constexpr (MODE == 3) { HOLDI(gx4[0]); HOLDI(gx4[1]); HOLDI(gx4[2]); HOLDI(gx4[3]); }

    // ---- h-phase: 24 coherent loads, per-4 pipelined vmcnt (exact counts) ----
    i32x4 hr[6][4];
#pragma unroll
    for (int i = 0; i < 6; ++i) {
      const int hoff = (wave * 6 + i) * 32 + quad * 8;  // h-dim in [0,768)
#pragma unroll
      for (int rt = 0; rt < 4; ++rt)
        hr[i][rt] = ldg_c16(hcur + (size_t)(rt * 16 + l15) * 768 + hoff);
    }
    HSTEP(0, "20")
    HSTEP(1, "16")
    HSTEP(2, "12")
    HSTEP(3, "8")
    HSTEP(4, "4")
    HSTEP(5, "0")

    // ---- write partials (col-major, b128): C/D col=lane&15, row=quad*4+reg
#pragma unroll
    for (int rt = 0; rt < 4; ++rt) {
      *(f32x4*)&gacc2[wave][l15][rt * 16 + quad * 4]      = acc[rt][0];
      *(f32x4*)&gacc2[wave][16 + l15][rt * 16 + quad * 4] = acc[rt][1];
    }
    __syncthreads();

    // ---- elementwise update (thread = batch bb, dims ed0,ed0+1) ----
    f32x2 kt2 = __builtin_bit_cast(f32x2, ktraw);
    float gs[2][4];
#pragma unroll
    for (int dd = 0; dd < 2; ++dd)
#pragma unroll
      for (int g = 0; g < 4; ++g) {
        float s = 0.f;
#pragma unroll
        for (int w = 0; w < 4; ++w) s += gacc2[w][g * 8 + dq * 2 + dd][bb];
        if constexpr (MODE == 2)
          s += __builtin_bit_cast(f32x2, gx8[g])[dd];
        if constexpr (MODE == 3)
          s += (float)__builtin_bit_cast(f16x2, gx4[g])[dd];
        gs[dd][g] = s;
      }
    f32x2 cnv, hnv;
#pragma unroll
    for (int dd = 0; dd < 2; ++dd) {
      float c_prev = creg[dd], h_prev = hreg[dd], kt = kt2[dd];
      float gi = gs[dd][0] + bi2[dd] + wpi2[dd] * c_prev;
      float gf = gs[dd][1] + bf2[dd] + wpf2[dd] * c_prev;
      float go = gs[dd][2] + bo2[dd] + wpo2[dd] * c_prev;
      float gc = gs[dd][3] + bc2[dd];
      float iv = sigm_f(gi);
      float fv = sigm_f(gf);
      float ov = sigm_f(go);
      float cp = fv * c_prev + iv * tanh_f(gc);
      float cn = kt * cp + (1.f - kt) * c_prev;
      float hp = tanh_f(cp) * ov;
      float hn = kt * hp + (1.f - kt) * h_prev;
      cnv[dd] = cn; hnv[dd] = hn;
    }
    creg = cnv; hreg = hnv;

    // h store (coherent, packed dword), per-wave drain, per-wave flag,
    // then barrier (gacc2 hazard), then deferred out store.
    __bf16 h0 = (__bf16)hnv[0], h1 = (__bf16)hnv[1];
    unsigned hu = (unsigned)__builtin_bit_cast(unsigned short, h0) |
                  ((unsigned)__builtin_bit_cast(unsigned short, h1) << 16);
    stg_c4(hnxt + (size_t)bb * 768 + ed0, (int)hu);
    waitcnt_vm0();                       // this wave's h stores at coherence pt
    if (lane == 0) stg_c4(flags + (j * 4 + wave) * 16, t + 1);
    __syncthreads();                     // gacc2 read/write hazard across steps
    f32x2 ov2; ov2[0] = hnv[0]; ov2[1] = hnv[1];
    stg_n8(out + ((size_t)bb * 512 + t) * 768 + ed0, __builtin_bit_cast(i32x2, ov2));
  }
}

// ---------------- launch ----------------
extern "C" void kernel_launch(void* const* d_in, const int* in_sizes, int n_in,
                              void* d_out, int out_size, void* d_ws, size_t ws_size,
                              hipStream_t stream) {
  const float* x     = (const float*)d_in[0];
  const float* W     = (const float*)d_in[1];
  const float* U     = (const float*)d_in[2];
  const float* bias  = (const float*)d_in[3];
  const float* wpeep = (const float*)d_in[4];
  const float* tau   = (const float*)d_in[5];
  const float* shift = (const float*)d_in[6];
  float* out = (float*)d_out;
  char* ws = (char*)d_ws;

  int*    flags = (int*)(ws + OFF_FLAGS);
  __bf16* hb0 = (__bf16*)(ws + OFF_HBUF0);
  __bf16* hb1 = (__bf16*)(ws + OFF_HBUF1);
  float*  kT  = (float*)(ws + OFF_KTAB);
  __bf16* WT  = (__bf16*)(ws + OFF_WT);
  __bf16* xb  = (__bf16*)(ws + OFF_XB);
  void*   gxp = (void*)(ws + OFF_GX);

  int mode;
  if      (ws_size >= WS_NEED_GXF32) mode = 2;
  else if (ws_size >= WS_NEED_GXF16) mode = 3;
  else if (ws_size >= WS_NEED_FULL)  mode = 1;
  else                               mode = 0;

  hipMemsetAsync(ws, 0, OFF_KTAB, stream);  // flags + both h buffers = 0
  k_wcomb<<<48 * 96, 256, 0, stream>>>(W, U, WT);
  k_ktab<<<(512 * 768) / 256, 256, 0, stream>>>(tau, shift, kT);

  if (mode == 2) {
    k_xgemm<0><<<256 * 24, 256, 0, stream>>>(x, WT, gxp);
    k_lstm<2><<<G_BLOCKS, 256, 0, stream>>>(nullptr, x, gxp, WT, kT, bias, wpeep,
                                            hb0, hb1, out, flags);
  } else if (mode == 3) {
    k_xgemm<1><<<256 * 24, 256, 0, stream>>>(x, WT, gxp);
    k_lstm<3><<<G_BLOCKS, 256, 0, stream>>>(nullptr, x, gxp, WT, kT, bias, wpeep,
                                            hb0, hb1, out, flags);
  } else if (mode == 1) {
    k_xb<<<(512 * 64 * 768) / 256, 256, 0, stream>>>(x, xb);
    k_lstm<1><<<G_BLOCKS, 256, 0, stream>>>(xb, x, nullptr, WT, kT, bias, wpeep,
                                            hb0, hb1, out, flags);
  } else {
    k_lstm<0><<<G_BLOCKS, 256, 0, stream>>>(nullptr, x, nullptr, WT, kT, bias, wpeep,
                                            hb0, hb1, out, flags);
  }
}